// Round 8
// baseline (80.206 us; speedup 1.0000x reference)
//
#include <hip/hip_runtime.h>

// NALU B=1024, I=512, O=512 — SINGLE dispatch, fp16 MFMA 16x16x32.
//   w1 = tanh(w_hat)*sigmoid(m_hat); a = x@w1; s = log(max(|x|,eps))@w1
//   m1 = exp(min(s,20)); out = g1*a + (1-g1)*m1*clip(ms,-1,1)
// s ~ N(-143,11^2) => m1 underflows to 0; guarded exactly: any s > -80
// takes a cold path computing the true sign-product from wh/mh.
//
// Why fuse (3rd attempt): cross-round budget decomposition shows each extra
// dispatch costs ~7-14 us of graph-node overhead; kernels themselves are
// small. R6's fusion failures fixed by: (a) NO A-staging -- MFMA A-frags are
// k-contiguous in x, loaded straight from global in the loop, log computed
// in-register; (b) B staged ONCE per block (raw tile -> frag-ordered LDS),
// then a barrier-free 16-iter loop of dwordx4 + ds_read_b128 + MFMA;
// (c) 512 blocks = 2 independent blocks/CU so staging stalls overlap.
// Frag layouts (learn_hip-verified): A[m=lane&15][k=(lane>>4)*8+j],
// B[k=(lane>>4)*8+j][n=lane&15], D[m=(lane>>4)*4+reg][n=lane&15].

#define O_N 512
#define I_N 512
#define B_N 1024

typedef _Float16 f16;
typedef _Float16 f16x4 __attribute__((ext_vector_type(4)));
typedef _Float16 f16x8 __attribute__((ext_vector_type(8)));
typedef float f32x4 __attribute__((ext_vector_type(4)));

__device__ __forceinline__ float fast_sigmoid(float v) {
    return 1.0f / (1.0f + __expf(-v));
}
__device__ __forceinline__ float fast_tanh(float v) {
    return 1.0f - 2.0f / (1.0f + __expf(2.0f * v));   // exact at both tails
}

__global__ __launch_bounds__(256, 2) void nalu_fused_kernel(const float* __restrict__ x,
                                                            const float* __restrict__ wh,
                                                            const float* __restrict__ mh,
                                                            const float* __restrict__ g,
                                                            float* __restrict__ out) {
    __shared__ f16x8 lbf[2][16][64];   // 32 KB frag-ordered w1 [nt][tk][lane]
    __shared__ f16   raw[256][36];     // 18 KB raw half-K tile, +4 pad/row

    const int tid  = threadIdx.x;
    const int lane = tid & 63;
    const int w    = tid >> 6;
    const int mi   = w & 1;            // m-subtile (16 b-rows)
    const int nt   = w >> 1;           // n-subtile (16 o-cols)
    const int o0   = blockIdx.x * 32;
    const int b0   = blockIdx.y * 32;

    // ---- stage B once: two K-halves of 256 through the raw tile ----
    for (int h = 0; h < 2; ++h) {
        const int kbase = h * 256;
        // phase 1: coalesced row reads (8 lanes x 128B per row), transcend, raw tile
#pragma unroll
        for (int s = 0; s < 8; ++s) {
            const int kl = s * 32 + (tid >> 3);          // 0..255
            const int n0 = (tid & 7) * 4;
            const int idx = (kbase + kl) * O_N + o0 + n0;
            const float4 wa = *(const float4*)(wh + idx);
            const float4 ma = *(const float4*)(mh + idx);
            f16x4 bv;
            bv[0] = (f16)(fast_tanh(wa.x) * fast_sigmoid(ma.x));
            bv[1] = (f16)(fast_tanh(wa.y) * fast_sigmoid(ma.y));
            bv[2] = (f16)(fast_tanh(wa.z) * fast_sigmoid(ma.z));
            bv[3] = (f16)(fast_tanh(wa.w) * fast_sigmoid(ma.w));
            *(f16x4*)&raw[kl][n0] = bv;                  // aligned b64
        }
        __syncthreads();
        // phase 2: gather 4 frags/thread from raw, write frag-ordered (b128)
#pragma unroll
        for (int i = 0; i < 4; ++i) {
            const int f   = i * 256 + tid;               // 0..1023
            const int fl  = f & 63;
            const int tkl = (f >> 6) & 7;
            const int fnt = f >> 9;                      // 0..1
            const int k0l = tkl * 32 + ((fl >> 4) & 3) * 8;
            const int n   = fnt * 16 + (fl & 15);
            f16x8 bf;
#pragma unroll
            for (int j = 0; j < 8; ++j) bf[j] = raw[k0l + j][n];
            lbf[fnt][h * 8 + tkl][fl] = bf;
        }
        __syncthreads();                                 // raw reused next half
    }

    // ---- barrier-free main loop: A straight from x, log in-register ----
    const int m  = b0 + mi * 16 + (lane & 15);
    const int k0 = (lane >> 4) * 8;
    const float* px = x + m * I_N + k0;

    f32x4 ca = {0.f, 0.f, 0.f, 0.f}, cs = ca;

#pragma unroll 4
    for (int tk = 0; tk < 16; ++tk) {
        const float4 q0 = *(const float4*)(px + tk * 32);
        const float4 q1 = *(const float4*)(px + tk * 32 + 4);
        const float vx[8] = {q0.x, q0.y, q0.z, q0.w, q1.x, q1.y, q1.z, q1.w};
        f16x8 fx, fv;
#pragma unroll
        for (int j = 0; j < 8; ++j) {
            fx[j] = (f16)vx[j];
            fv[j] = (f16)__logf(fmaxf(fabsf(vx[j]), 1e-7f));
        }
        const f16x8 bf = lbf[nt][tk][lane];
        ca = __builtin_amdgcn_mfma_f32_16x16x32_f16(fx, bf, ca, 0, 0, 0);
        cs = __builtin_amdgcn_mfma_f32_16x16x32_f16(fv, bf, cs, 0, 0, 0);
    }

    // ---- epilogue: D[m=(lane>>4)*4+r][n=lane&15] ----
    const int col = lane & 15;
    const int rq  = (lane >> 4) * 4;
    const int o   = o0 + nt * 16 + col;
    const int bb  = b0 + mi * 16 + rq;
    const float g1  = fast_sigmoid(g[o]);
    const float omg = 1.0f - g1;
#pragma unroll
    for (int r = 0; r < 4; ++r) {
        const int b = bb + r;
        const float sv = cs[r];
        const float m1 = __expf(fminf(sv, 20.0f));
        float msv = 1.0f;
        if (sv > -80.0f) {                  // cold path (expected never): exact ms
            float p = 1.0f;
            for (int i = 0; i < I_N; ++i) {
                // ws_oi[o][i] = |w1.flat[o*I+i]| = |w1[row=o][col=i]|
                const float wv = fabsf(fast_tanh(wh[o * I_N + i]) *
                                       fast_sigmoid(mh[o * I_N + i]));
                const float xv = x[b * I_N + i];
                const float sg = (xv > 0.f) ? 1.f : ((xv < 0.f) ? -1.f : 0.f);
                p *= sg * wv + (1.0f - wv);
            }
            msv = fminf(fmaxf(p, -1.0f), 1.0f);
        }
        out[b * O_N + o] = g1 * ca[r] + omg * m1 * msv;
    }
}

extern "C" void kernel_launch(void* const* d_in, const int* in_sizes, int n_in,
                              void* d_out, int out_size, void* d_ws, size_t ws_size,
                              hipStream_t stream) {
    const float* x  = (const float*)d_in[0];   // [B, I]
    const float* wh = (const float*)d_in[1];   // [I, O]
    const float* mh = (const float*)d_in[2];   // [I, O]
    const float* g  = (const float*)d_in[3];   // [O]
    float* out = (float*)d_out;                // [B, O] fp32

    (void)d_ws; (void)ws_size;                 // scratch unused

    nalu_fused_kernel<<<dim3(O_N / 32, B_N / 32), 256, 0, stream>>>(x, wh, mh, g, out);
}